// Round 6
// baseline (445.904 us; speedup 1.0000x reference)
//
#include <hip/hip_runtime.h>
#include <hip/hip_bf16.h>
#include <stdint.h>

// Round 6: full fused MFMA design (round-1 architecture) with FLOAT32 output
// stores. Root cause of rounds 0-5: d_out is f32 (reference output dtype);
// bf16-u16 stores aliased into f32 words -> decorrelated-neighbor signature
// (absmax 6.4375 = max|ref - alias| over 67M, 4.21875 = max|ref| on zeros).
// rows M = F*N = 262144.  GEMM1: [M,288]x[288,144] (K-tile 8 = one-hot)
// GEMM2: [M,160]x[160,256]  GEMM3: [M,512]x[512,32] (cols>=24 dropped).
// All MFMA = v_mfma_f32_16x16x32_bf16; weights packed to B-frag order (g_wpack).

typedef __attribute__((ext_vector_type(8))) short short8;
typedef __attribute__((ext_vector_type(4))) float float4v;

#define MFMA16 __builtin_amdgcn_mfma_f32_16x16x32_bf16

__device__ __align__(16) uint16_t g_wpack[98816];

__device__ __forceinline__ uint16_t f2bf(float f) {
    uint32_t u = __float_as_uint(f);
    u += 0x7FFFu + ((u >> 16) & 1u);   // RNE
    return (uint16_t)(u >> 16);
}

__device__ __forceinline__ short8 cvt8(float4v x0, float4v x1) {
    short8 a;
    a[0] = (short)f2bf(x0[0]); a[1] = (short)f2bf(x0[1]);
    a[2] = (short)f2bf(x0[2]); a[3] = (short)f2bf(x0[3]);
    a[4] = (short)f2bf(x1[0]); a[5] = (short)f2bf(x1[1]);
    a[6] = (short)f2bf(x1[2]); a[7] = (short)f2bf(x1[3]);
    return a;
}

// ---- weight packing into g_wpack (B-fragment order) ----
// W1p: 9kt x 9nt (K=288 pad, N=144 pad) @u16 0      (41472)
// W2p: 5kt x 16nt (K=160 pad, N=256)    @u16 41472  (40960)
// Wip: 16kt x 2nt (K=512,    N=32 pad)  @u16 82432  (16384)
__global__ __launch_bounds__(256) void pack_weights(
    const float* __restrict__ W1, const float* __restrict__ W2,
    const float* __restrict__ Wi)
{
    int e = blockIdx.x * 256 + threadIdx.x;
    const float* W; int NT, Kr, Nr, ld, le, base;
    if (e < 41472)      { W = W1; NT = 9;  Kr = 280; Nr = 140; ld = 140; le = e;         base = 0; }
    else if (e < 82432) { W = W2; NT = 16; Kr = 140; Nr = 256; ld = 256; le = e - 41472; base = 41472; }
    else if (e < 98816) { W = Wi; NT = 2;  Kr = 512; Nr = 24;  ld = 24;  le = e - 82432; base = 82432; }
    else return;
    int i = le & 7, lane = (le >> 3) & 63, frag = le >> 9;
    int kt = frag / NT, nt = frag - kt * NT;
    int k = kt * 32 + ((lane >> 4) << 3) + i;
    int n = nt * 16 + (lane & 15);
    float v = (k < Kr && n < Nr) ? W[k * ld + n] : 0.0f;
    g_wpack[base + le] = f2bf(v);
}

// ---- main fused kernel: 256 threads = 4 waves, each wave 32 rows ----
__global__ __launch_bounds__(256) void icm_main(
    const float* __restrict__ cf, const float* __restrict__ nf,
    const int* __restrict__ act,
    const float* __restrict__ b1, const float* __restrict__ b2,
    const float* __restrict__ bi,
    float* __restrict__ out)
{
    // wave-private h buffer: 32 rows x 192 cols bf16 (384 B stride, XOR swizzle)
    __shared__ char hbuf[4 * 32 * 384];

    const int tid  = threadIdx.x;
    const int wave = tid >> 6;
    const int lane = tid & 63;
    const int lhi  = lane >> 4;   // 0..3
    const int llo  = lane & 15;   // 0..15
    char* hb = hbuf + wave * (32 * 384);

    const long rowbase = (long)blockIdx.x * 128 + wave * 32;

    const short8* wp  = (const short8*)g_wpack;  // frag chunks: fragIdx*64 + lane
    const int W2_BASE = 81 * 64;                 // 5184
    const int WI_BASE = 161 * 64;                // 10304

    const float4v fz = {0.f, 0.f, 0.f, 0.f};
    float4v acc1[2][9];
    float4v acc3[2][2];
    #pragma unroll
    for (int m = 0; m < 2; ++m) {
        #pragma unroll
        for (int n = 0; n < 9; ++n) acc1[m][n] = fz;
        acc3[m][0] = fz; acc3[m][1] = fz;
    }

    // actions for this lane's rows (row = rowbase + m*16 + llo)
    int i0[2], i1[2], i2[2];
    #pragma unroll
    for (int m = 0; m < 2; ++m) {
        long r = rowbase + m * 16 + llo;
        long f = r >> 6; int n = (int)(r & 63);
        i0[m] = act[(f * 3 + 0) * 64 + n];
        i1[m] = act[(f * 3 + 1) * 64 + n] + 8;
        i2[m] = act[(f * 3 + 2) * 64 + n] + 16;
    }

    // ---- GEMM1 (K-tiles 0..7 from cf) fused with GEMM3 first half ----
    #pragma unroll
    for (int kt = 0; kt < 8; ++kt) {
        short8 a[2];
        #pragma unroll
        for (int m = 0; m < 2; ++m) {
            long r = rowbase + m * 16 + llo;
            const float* p = cf + r * 256 + kt * 32 + lhi * 8;
            a[m] = cvt8(*(const float4v*)p, *(const float4v*)(p + 4));
        }
        #pragma unroll
        for (int nt = 0; nt < 9; ++nt) {
            short8 bf = wp[(kt * 9 + nt) * 64 + lane];
            acc1[0][nt] = MFMA16(a[0], bf, acc1[0][nt], 0, 0, 0);
            acc1[1][nt] = MFMA16(a[1], bf, acc1[1][nt], 0, 0, 0);
        }
        #pragma unroll
        for (int nt = 0; nt < 2; ++nt) {
            short8 bf = wp[WI_BASE + (kt * 2 + nt) * 64 + lane];
            acc3[0][nt] = MFMA16(a[0], bf, acc3[0][nt], 0, 0, 0);
            acc3[1][nt] = MFMA16(a[1], bf, acc3[1][nt], 0, 0, 0);
        }
    }
    // K-tile 8: one-hot action block (k = 256..287, kk = k-256)
    {
        short8 a[2];
        #pragma unroll
        for (int m = 0; m < 2; ++m) {
            #pragma unroll
            for (int i = 0; i < 8; ++i) {
                int kk = lhi * 8 + i;
                a[m][i] = (kk == i0[m] || kk == i1[m] || kk == i2[m])
                              ? (short)0x3F80 : (short)0;
            }
        }
        #pragma unroll
        for (int nt = 0; nt < 9; ++nt) {
            short8 bf = wp[(8 * 9 + nt) * 64 + lane];
            acc1[0][nt] = MFMA16(a[0], bf, acc1[0][nt], 0, 0, 0);
            acc1[1][nt] = MFMA16(a[1], bf, acc1[1][nt], 0, 0, 0);
        }
    }

    // ---- epilogue 1: bias + leaky_relu(0.1) -> bf16 -> swizzled LDS ----
    // (pad cols 140..143 get garbage; W2 pack zeroes k>=140 so they're inert)
    #pragma unroll
    for (int m = 0; m < 2; ++m) {
        #pragma unroll
        for (int nt = 0; nt < 9; ++nt) {
            int col = nt * 16 + llo;
            float bb = b1[col < 140 ? col : 139];
            #pragma unroll
            for (int r = 0; r < 4; ++r) {
                float v = acc1[m][nt][r] + bb;
                v = v > 0.f ? v : 0.1f * v;
                int row = m * 16 + lhi * 4 + r;
                int off = row * 384 + col * 2;
                off ^= (row & 7) << 4;
                *(uint16_t*)(hb + off) = f2bf(v);
            }
        }
    }
    // zero h cols 144..159 (GEMM2 K-pad; also inert, but keep LDS defined)
    #pragma unroll
    for (int z = 0; z < 4; ++z) {
        int zz  = lane * 4 + z;            // 0..255
        int row = zz >> 3, d = zz & 7;
        int off = row * 384 + 288 + d * 4;
        off ^= (row & 7) << 4;
        *(int*)(hb + off) = 0;
    }

    __syncthreads();   // order LDS writes vs b128 reads

    // ---- GEMM2: out0 = leaky(h) @ W2 + b2  (two n-halves to cap VGPRs) ----
    #pragma unroll 1
    for (int pass = 0; pass < 2; ++pass) {
        float4v acc2[2][8];
        #pragma unroll
        for (int m = 0; m < 2; ++m)
            #pragma unroll
            for (int n = 0; n < 8; ++n) acc2[m][n] = fz;

        #pragma unroll
        for (int kt = 0; kt < 5; ++kt) {
            short8 a[2];
            #pragma unroll
            for (int m = 0; m < 2; ++m) {
                int row = m * 16 + llo;
                int off = row * 384 + (kt * 32 + lhi * 8) * 2;
                off ^= (row & 7) << 4;
                a[m] = *(const short8*)(hb + off);
            }
            #pragma unroll
            for (int n = 0; n < 8; ++n) {
                int nt = pass * 8 + n;
                short8 bf = wp[W2_BASE + (kt * 16 + nt) * 64 + lane];
                acc2[0][n] = MFMA16(a[0], bf, acc2[0][n], 0, 0, 0);
                acc2[1][n] = MFMA16(a[1], bf, acc2[1][n], 0, 0, 0);
            }
        }
        #pragma unroll
        for (int m = 0; m < 2; ++m) {
            #pragma unroll
            for (int n = 0; n < 8; ++n) {
                int col = (pass * 8 + n) * 16 + llo;
                float bb = b2[col];
                #pragma unroll
                for (int r = 0; r < 4; ++r) {
                    long row = rowbase + m * 16 + lhi * 4 + r;
                    out[row * 256 + col] = acc2[m][n][r] + bb;   // f32 store
                }
            }
        }
    }

    // ---- GEMM3 second half (nf, k=256..511) ----
    #pragma unroll
    for (int kt = 0; kt < 8; ++kt) {
        short8 a[2];
        #pragma unroll
        for (int m = 0; m < 2; ++m) {
            long r = rowbase + m * 16 + llo;
            const float* p = nf + r * 256 + kt * 32 + lhi * 8;
            a[m] = cvt8(*(const float4v*)p, *(const float4v*)(p + 4));
        }
        #pragma unroll
        for (int nt = 0; nt < 2; ++nt) {
            short8 bf = wp[WI_BASE + ((8 + kt) * 2 + nt) * 64 + lane];
            acc3[0][nt] = MFMA16(a[0], bf, acc3[0][nt], 0, 0, 0);
            acc3[1][nt] = MFMA16(a[1], bf, acc3[1][nt], 0, 0, 0);
        }
    }
    // store action_pred (cols < 24), f32
    float* out2 = out + 67108864L;
    #pragma unroll
    for (int m = 0; m < 2; ++m) {
        #pragma unroll
        for (int nt = 0; nt < 2; ++nt) {
            int col = nt * 16 + llo;
            if (col < 24) {
                float bb = bi[col];
                #pragma unroll
                for (int r = 0; r < 4; ++r) {
                    long row = rowbase + m * 16 + lhi * 4 + r;
                    out2[row * 24 + col] = acc3[m][nt][r] + bb;   // f32 store
                }
            }
        }
    }
}

extern "C" void kernel_launch(void* const* d_in, const int* in_sizes, int n_in,
                              void* d_out, int out_size, void* d_ws, size_t ws_size,
                              hipStream_t stream) {
    // Identify inputs by unique element count (verified: matches dict order).
    const float *cf = nullptr, *nf = nullptr, *W1 = nullptr, *b1 = nullptr;
    const float *W2 = nullptr, *b2 = nullptr, *Wi = nullptr, *bi = nullptr;
    const int *ac = nullptr;
    for (int i = 0; i < n_in; ++i) {
        int s = in_sizes[i];
        const void* p = d_in[i];
        switch (s) {
            case 67108864: if (!cf) cf = (const float*)p; else nf = (const float*)p; break;
            case 786432:   ac = (const int*)p;   break;
            case 39200:    W1 = (const float*)p; break;
            case 140:      b1 = (const float*)p; break;
            case 35840:    W2 = (const float*)p; break;
            case 256:      b2 = (const float*)p; break;
            case 12288:    Wi = (const float*)p; break;
            case 24:       bi = (const float*)p; break;
            default: break;
        }
    }
    float* ob = (float*)d_out;

    pack_weights<<<386, 256, 0, stream>>>(W1, W2, Wi);
    icm_main<<<2048, 256, 0, stream>>>(cf, nf, ac, b1, b2, bi, ob);
}

// Round 7
// 353.445 us; speedup vs baseline: 1.2616x; 1.2616x over previous
//
#include <hip/hip_runtime.h>
#include <hip/hip_bf16.h>
#include <stdint.h>

// Round 7: latency/occupancy attack on the passing round-6 kernel.
//  - LDS 48KB -> 40KB (hA 256B/row swz(row&7), hB 64B/row swz(row&3)) => 4 blocks/CU
//  - __launch_bounds__(256,4) => VGPR<=128 => 4 waves/SIMD => 16 waves/CU
//  - rolled K-loops + 1-deep feature prefetch (HBM latency under MFMA block)
//  - GEMM3b before GEMM2 (acc3 dead before acc2 lives)
// Semantics identical to round 6 (PASS, absmax 0.031).

typedef __attribute__((ext_vector_type(8))) short short8;
typedef __attribute__((ext_vector_type(4))) float float4v;

#define MFMA16 __builtin_amdgcn_mfma_f32_16x16x32_bf16

__device__ __align__(16) uint16_t g_wpack[98816];

__device__ __forceinline__ uint16_t f2bf(float f) {
    uint32_t u = __float_as_uint(f);
    u += 0x7FFFu + ((u >> 16) & 1u);   // RNE
    return (uint16_t)(u >> 16);
}

__device__ __forceinline__ short8 cvt8(float4v x0, float4v x1) {
    short8 a;
    a[0] = (short)f2bf(x0[0]); a[1] = (short)f2bf(x0[1]);
    a[2] = (short)f2bf(x0[2]); a[3] = (short)f2bf(x0[3]);
    a[4] = (short)f2bf(x1[0]); a[5] = (short)f2bf(x1[1]);
    a[6] = (short)f2bf(x1[2]); a[7] = (short)f2bf(x1[3]);
    return a;
}

// ---- weight packing into g_wpack (B-fragment order) ----
// W1p: 9kt x 9nt (K=288 pad, N=144 pad) @u16 0      (41472)
// W2p: 5kt x 16nt (K=160 pad, N=256)    @u16 41472  (40960)
// Wip: 16kt x 2nt (K=512,    N=32 pad)  @u16 82432  (16384)
__global__ __launch_bounds__(256) void pack_weights(
    const float* __restrict__ W1, const float* __restrict__ W2,
    const float* __restrict__ Wi)
{
    int e = blockIdx.x * 256 + threadIdx.x;
    const float* W; int NT, Kr, Nr, ld, le, base;
    if (e < 41472)      { W = W1; NT = 9;  Kr = 280; Nr = 140; ld = 140; le = e;         base = 0; }
    else if (e < 82432) { W = W2; NT = 16; Kr = 140; Nr = 256; ld = 256; le = e - 41472; base = 41472; }
    else if (e < 98816) { W = Wi; NT = 2;  Kr = 512; Nr = 24;  ld = 24;  le = e - 82432; base = 82432; }
    else return;
    int i = le & 7, lane = (le >> 3) & 63, frag = le >> 9;
    int kt = frag / NT, nt = frag - kt * NT;
    int k = kt * 32 + ((lane >> 4) << 3) + i;
    int n = nt * 16 + (lane & 15);
    float v = (k < Kr && n < Nr) ? W[k * ld + n] : 0.0f;
    g_wpack[base + le] = f2bf(v);
}

// ---- main fused kernel: 256 threads = 4 waves, each wave 32 rows ----
__global__ __launch_bounds__(256, 4) void icm_main(
    const float* __restrict__ cf, const float* __restrict__ nf,
    const int* __restrict__ act,
    const float* __restrict__ b1, const float* __restrict__ b2,
    const float* __restrict__ bi,
    float* __restrict__ out)
{
    // hA: [4 waves][32 rows][256B] cols 0..127, swz ^((row&7)<<4)  (32768 B)
    // hB: [4 waves][32 rows][ 64B] cols 128..159, swz ^((row&3)<<4) ( 8192 B)
    __shared__ char hbuf[40960];

    const int tid  = threadIdx.x;
    const int wave = tid >> 6;
    const int lane = tid & 63;
    const int lhi  = lane >> 4;   // 0..3
    const int llo  = lane & 15;   // 0..15
    char* hA = hbuf + wave * 8192;
    char* hB = hbuf + 32768 + wave * 2048;

    const long rowbase = (long)blockIdx.x * 128 + wave * 32;

    const short8* wp  = (const short8*)g_wpack;  // frag chunks: fragIdx*64 + lane
    const int W2_BASE = 81 * 64;                 // 5184
    const int WI_BASE = 161 * 64;                // 10304

    // prefetch actions for this lane's rows (row = rowbase + m*16 + llo)
    int i0[2], i1[2], i2[2];
    #pragma unroll
    for (int m = 0; m < 2; ++m) {
        long r = rowbase + m * 16 + llo;
        long f = r >> 6; int n = (int)(r & 63);
        i0[m] = act[(f * 3 + 0) * 64 + n];
        i1[m] = act[(f * 3 + 1) * 64 + n] + 8;
        i2[m] = act[(f * 3 + 2) * 64 + n] + 16;
    }

    const float4v fz = {0.f, 0.f, 0.f, 0.f};
    float4v acc1[2][9];
    float4v acc3[2][2];
    #pragma unroll
    for (int m = 0; m < 2; ++m) {
        #pragma unroll
        for (int n = 0; n < 9; ++n) acc1[m][n] = fz;
        acc3[m][0] = fz; acc3[m][1] = fz;
    }

    // per-m feature base pointers (lane-fixed part folded in)
    const float* cfb[2];
    #pragma unroll
    for (int m = 0; m < 2; ++m)
        cfb[m] = cf + (rowbase + m * 16 + llo) * 256 + lhi * 8;

    // ---- GEMM1 (cf) + GEMM3 first half, rolled + 1-deep prefetch ----
    float4v x0[2], x1[2];
    #pragma unroll
    for (int m = 0; m < 2; ++m) {
        x0[m] = *(const float4v*)(cfb[m]);
        x1[m] = *(const float4v*)(cfb[m] + 4);
    }
    #pragma unroll 1
    for (int kt = 0; kt < 8; ++kt) {
        short8 a[2];
        a[0] = cvt8(x0[0], x1[0]);
        a[1] = cvt8(x0[1], x1[1]);
        if (kt < 7) {
            #pragma unroll
            for (int m = 0; m < 2; ++m) {
                x0[m] = *(const float4v*)(cfb[m] + (kt + 1) * 32);
                x1[m] = *(const float4v*)(cfb[m] + (kt + 1) * 32 + 4);
            }
        }
        #pragma unroll
        for (int nt = 0; nt < 9; ++nt) {
            short8 bf = wp[(kt * 9 + nt) * 64 + lane];
            acc1[0][nt] = MFMA16(a[0], bf, acc1[0][nt], 0, 0, 0);
            acc1[1][nt] = MFMA16(a[1], bf, acc1[1][nt], 0, 0, 0);
        }
        #pragma unroll
        for (int nt = 0; nt < 2; ++nt) {
            short8 bf = wp[WI_BASE + (kt * 2 + nt) * 64 + lane];
            acc3[0][nt] = MFMA16(a[0], bf, acc3[0][nt], 0, 0, 0);
            acc3[1][nt] = MFMA16(a[1], bf, acc3[1][nt], 0, 0, 0);
        }
    }
    // K-tile 8: one-hot action block (k = 256..287, kk = k-256)
    {
        short8 a[2];
        #pragma unroll
        for (int m = 0; m < 2; ++m) {
            #pragma unroll
            for (int i = 0; i < 8; ++i) {
                int kk = lhi * 8 + i;
                a[m][i] = (kk == i0[m] || kk == i1[m] || kk == i2[m])
                              ? (short)0x3F80 : (short)0;
            }
        }
        #pragma unroll
        for (int nt = 0; nt < 9; ++nt) {
            short8 bf = wp[(8 * 9 + nt) * 64 + lane];
            acc1[0][nt] = MFMA16(a[0], bf, acc1[0][nt], 0, 0, 0);
            acc1[1][nt] = MFMA16(a[1], bf, acc1[1][nt], 0, 0, 0);
        }
    }

    // ---- epilogue 1: bias + leaky_relu(0.1) -> bf16 -> swizzled LDS ----
    #pragma unroll
    for (int m = 0; m < 2; ++m) {
        #pragma unroll
        for (int nt = 0; nt < 9; ++nt) {
            int col = nt * 16 + llo;
            float bb = b1[col < 140 ? col : 139];
            #pragma unroll
            for (int r = 0; r < 4; ++r) {
                float v = acc1[m][nt][r] + bb;
                v = v > 0.f ? v : 0.1f * v;
                int row = m * 16 + lhi * 4 + r;
                if (nt < 8) {
                    int off = row * 256 + ((col * 2) ^ ((row & 7) << 4));
                    *(uint16_t*)(hA + off) = f2bf(v);
                } else {
                    int off = row * 64 + (((col - 128) * 2) ^ ((row & 3) << 4));
                    *(uint16_t*)(hB + off) = f2bf(v);
                }
            }
        }
    }
    // zero hB cols 144..159 (GEMM2 K-pad; W2p also zeroed there, belt+braces)
    #pragma unroll
    for (int z = 0; z < 4; ++z) {
        int zz  = lane * 4 + z;            // 0..255
        int row = zz >> 3, d = zz & 7;
        int off = row * 64 + ((32 + d * 4) ^ ((row & 3) << 4));
        *(int*)(hB + off) = 0;
    }

    __syncthreads();

    // ---- GEMM3 second half (nf, k=256..511), rolled + prefetch ----
    const float* nfb[2];
    #pragma unroll
    for (int m = 0; m < 2; ++m)
        nfb[m] = nf + (rowbase + m * 16 + llo) * 256 + lhi * 8;
    #pragma unroll
    for (int m = 0; m < 2; ++m) {
        x0[m] = *(const float4v*)(nfb[m]);
        x1[m] = *(const float4v*)(nfb[m] + 4);
    }
    #pragma unroll 1
    for (int kt = 0; kt < 8; ++kt) {
        short8 a[2];
        a[0] = cvt8(x0[0], x1[0]);
        a[1] = cvt8(x0[1], x1[1]);
        if (kt < 7) {
            #pragma unroll
            for (int m = 0; m < 2; ++m) {
                x0[m] = *(const float4v*)(nfb[m] + (kt + 1) * 32);
                x1[m] = *(const float4v*)(nfb[m] + (kt + 1) * 32 + 4);
            }
        }
        #pragma unroll
        for (int nt = 0; nt < 2; ++nt) {
            short8 bf = wp[WI_BASE + ((8 + kt) * 2 + nt) * 64 + lane];
            acc3[0][nt] = MFMA16(a[0], bf, acc3[0][nt], 0, 0, 0);
            acc3[1][nt] = MFMA16(a[1], bf, acc3[1][nt], 0, 0, 0);
        }
    }
    // store action_pred (cols < 24), f32
    float* out2 = out + 67108864L;
    #pragma unroll
    for (int m = 0; m < 2; ++m) {
        #pragma unroll
        for (int nt = 0; nt < 2; ++nt) {
            int col = nt * 16 + llo;
            if (col < 24) {
                float bb = bi[col];
                #pragma unroll
                for (int r = 0; r < 4; ++r) {
                    long row = rowbase + m * 16 + lhi * 4 + r;
                    out2[row * 24 + col] = acc3[m][nt][r] + bb;
                }
            }
        }
    }

    // ---- GEMM2: out0 = leaky(h) @ W2 + b2  (two n-halves to cap VGPRs) ----
    #pragma unroll 1
    for (int pass = 0; pass < 2; ++pass) {
        float4v acc2[2][8];
        #pragma unroll
        for (int m = 0; m < 2; ++m)
            #pragma unroll
            for (int n = 0; n < 8; ++n) acc2[m][n] = fz;

        #pragma unroll
        for (int kt = 0; kt < 5; ++kt) {
            short8 a[2];
            #pragma unroll
            for (int m = 0; m < 2; ++m) {
                int row = m * 16 + llo;
                if (kt < 4) {
                    int off = row * 256 + ((kt * 64 + lhi * 16) ^ ((row & 7) << 4));
                    a[m] = *(const short8*)(hA + off);
                } else {
                    int off = row * 64 + ((lhi * 16) ^ ((row & 3) << 4));
                    a[m] = *(const short8*)(hB + off);
                }
            }
            #pragma unroll
            for (int n = 0; n < 8; ++n) {
                int nt = pass * 8 + n;
                short8 bf = wp[W2_BASE + (kt * 16 + nt) * 64 + lane];
                acc2[0][n] = MFMA16(a[0], bf, acc2[0][n], 0, 0, 0);
                acc2[1][n] = MFMA16(a[1], bf, acc2[1][n], 0, 0, 0);
            }
        }
        #pragma unroll
        for (int m = 0; m < 2; ++m) {
            #pragma unroll
            for (int n = 0; n < 8; ++n) {
                int col = (pass * 8 + n) * 16 + llo;
                float bb = b2[col];
                #pragma unroll
                for (int r = 0; r < 4; ++r) {
                    long row = rowbase + m * 16 + lhi * 4 + r;
                    out[row * 256 + col] = acc2[m][n][r] + bb;
                }
            }
        }
    }
}

extern "C" void kernel_launch(void* const* d_in, const int* in_sizes, int n_in,
                              void* d_out, int out_size, void* d_ws, size_t ws_size,
                              hipStream_t stream) {
    // Identify inputs by unique element count (verified: matches dict order).
    const float *cf = nullptr, *nf = nullptr, *W1 = nullptr, *b1 = nullptr;
    const float *W2 = nullptr, *b2 = nullptr, *Wi = nullptr, *bi = nullptr;
    const int *ac = nullptr;
    for (int i = 0; i < n_in; ++i) {
        int s = in_sizes[i];
        const void* p = d_in[i];
        switch (s) {
            case 67108864: if (!cf) cf = (const float*)p; else nf = (const float*)p; break;
            case 786432:   ac = (const int*)p;   break;
            case 39200:    W1 = (const float*)p; break;
            case 140:      b1 = (const float*)p; break;
            case 35840:    W2 = (const float*)p; break;
            case 256:      b2 = (const float*)p; break;
            case 12288:    Wi = (const float*)p; break;
            case 24:       bi = (const float*)p; break;
            default: break;
        }
    }
    float* ob = (float*)d_out;

    pack_weights<<<386, 256, 0, stream>>>(W1, W2, Wi);
    icm_main<<<2048, 256, 0, stream>>>(cf, nf, ac, b1, b2, bi, ob);
}

// Round 8
// 244.414 us; speedup vs baseline: 1.8244x; 1.4461x over previous
//
#include <hip/hip_runtime.h>
#include <hip/hip_bf16.h>
#include <stdint.h>

// Round 8: de-spill + latency surgery on the passing round-7 kernel.
//  - __launch_bounds__(256,3): unified VGPR budget 170 (acc 88 + arch ~80),
//    removes the spill signature (+134MB FETCH/+161MB WRITE symmetric in r7).
//  - hardware bf16 cvt (v_cvt_pk_bf16_f32) instead of 4-op manual RNE.
//  - 2-deep feature prefetch (static two-slot ring) for ~900cyc HBM latency.
//  - no __syncthreads: h is wave-private LDS.
// Semantics identical to rounds 6/7 (PASS, absmax 0.031).

typedef __attribute__((ext_vector_type(8))) short short8;
typedef __attribute__((ext_vector_type(4))) float float4v;

#define MFMA16 __builtin_amdgcn_mfma_f32_16x16x32_bf16

__device__ __align__(16) uint16_t g_wpack[98816];

__device__ __forceinline__ uint16_t f2bf(float f) {
    __hip_bfloat16 h = __float2bfloat16(f);   // RNE, hw cvt
    return *reinterpret_cast<uint16_t*>(&h);
}

__device__ __forceinline__ short8 cvt8(float4v x0, float4v x1) {
    union { __hip_bfloat162 b2[4]; short8 s; } u;
    u.b2[0] = __float22bfloat162_rn(make_float2(x0[0], x0[1]));
    u.b2[1] = __float22bfloat162_rn(make_float2(x0[2], x0[3]));
    u.b2[2] = __float22bfloat162_rn(make_float2(x1[0], x1[1]));
    u.b2[3] = __float22bfloat162_rn(make_float2(x1[2], x1[3]));
    return u.s;
}

// ---- weight packing into g_wpack (B-fragment order) ----
// W1p: 9kt x 9nt (K=288 pad, N=144 pad) @u16 0      (41472)
// W2p: 5kt x 16nt (K=160 pad, N=256)    @u16 41472  (40960)
// Wip: 16kt x 2nt (K=512,    N=32 pad)  @u16 82432  (16384)
__global__ __launch_bounds__(256) void pack_weights(
    const float* __restrict__ W1, const float* __restrict__ W2,
    const float* __restrict__ Wi)
{
    int e = blockIdx.x * 256 + threadIdx.x;
    const float* W; int NT, Kr, Nr, ld, le, base;
    if (e < 41472)      { W = W1; NT = 9;  Kr = 280; Nr = 140; ld = 140; le = e;         base = 0; }
    else if (e < 82432) { W = W2; NT = 16; Kr = 140; Nr = 256; ld = 256; le = e - 41472; base = 41472; }
    else if (e < 98816) { W = Wi; NT = 2;  Kr = 512; Nr = 24;  ld = 24;  le = e - 82432; base = 82432; }
    else return;
    int i = le & 7, lane = (le >> 3) & 63, frag = le >> 9;
    int kt = frag / NT, nt = frag - kt * NT;
    int k = kt * 32 + ((lane >> 4) << 3) + i;
    int n = nt * 16 + (lane & 15);
    float v = (k < Kr && n < Nr) ? W[k * ld + n] : 0.0f;
    g_wpack[base + le] = f2bf(v);
}

// ---- main fused kernel: 256 threads = 4 waves, each wave 32 rows ----
__global__ __launch_bounds__(256, 3) void icm_main(
    const float* __restrict__ cf, const float* __restrict__ nf,
    const int* __restrict__ act,
    const float* __restrict__ b1, const float* __restrict__ b2,
    const float* __restrict__ bi,
    float* __restrict__ out)
{
    // hA: [4 waves][32 rows][256B] cols 0..127, swz ^((row&7)<<4)  (32768 B)
    // hB: [4 waves][32 rows][ 64B] cols 128..159, swz ^((row&3)<<4) ( 8192 B)
    __shared__ char hbuf[40960];

    const int tid  = threadIdx.x;
    const int wave = tid >> 6;
    const int lane = tid & 63;
    const int lhi  = lane >> 4;   // 0..3
    const int llo  = lane & 15;   // 0..15
    char* hA = hbuf + wave * 8192;
    char* hB = hbuf + 32768 + wave * 2048;

    const long rowbase = (long)blockIdx.x * 128 + wave * 32;

    const short8* wp  = (const short8*)g_wpack;  // frag chunks: fragIdx*64 + lane
    const int W2_BASE = 81 * 64;                 // 5184
    const int WI_BASE = 161 * 64;                // 10304

#define W1FRAG(KT, NT) wp[((KT) * 9 + (NT)) * 64 + lane]
#define WIFRAG(KT, NT) wp[WI_BASE + ((KT) * 2 + (NT)) * 64 + lane]

#define G1_STEP(KT, AA) do {                                         \
    _Pragma("unroll")                                                \
    for (int nt_ = 0; nt_ < 9; ++nt_) {                              \
        short8 bf_ = W1FRAG(KT, nt_);                                \
        acc1[0][nt_] = MFMA16(AA[0], bf_, acc1[0][nt_], 0, 0, 0);    \
        acc1[1][nt_] = MFMA16(AA[1], bf_, acc1[1][nt_], 0, 0, 0);    \
    }                                                                \
    _Pragma("unroll")                                                \
    for (int nt_ = 0; nt_ < 2; ++nt_) {                              \
        short8 bf_ = WIFRAG(KT, nt_);                                \
        acc3[0][nt_] = MFMA16(AA[0], bf_, acc3[0][nt_], 0, 0, 0);    \
        acc3[1][nt_] = MFMA16(AA[1], bf_, acc3[1][nt_], 0, 0, 0);    \
    }                                                                \
} while (0)

#define G3_STEP(KTA, AA) do {                                        \
    _Pragma("unroll")                                                \
    for (int nt_ = 0; nt_ < 2; ++nt_) {                              \
        short8 bf_ = WIFRAG(KTA, nt_);                               \
        acc3[0][nt_] = MFMA16(AA[0], bf_, acc3[0][nt_], 0, 0, 0);    \
        acc3[1][nt_] = MFMA16(AA[1], bf_, acc3[1][nt_], 0, 0, 0);    \
    }                                                                \
} while (0)

    // prefetch actions for this lane's rows (row = rowbase + m*16 + llo)
    int i0[2], i1[2], i2[2];
    #pragma unroll
    for (int m = 0; m < 2; ++m) {
        long r = rowbase + m * 16 + llo;
        long f = r >> 6; int n = (int)(r & 63);
        i0[m] = act[(f * 3 + 0) * 64 + n];
        i1[m] = act[(f * 3 + 1) * 64 + n] + 8;
        i2[m] = act[(f * 3 + 2) * 64 + n] + 16;
    }

    const float4v fz = {0.f, 0.f, 0.f, 0.f};
    float4v acc1[2][9];
    float4v acc3[2][2];
    #pragma unroll
    for (int m = 0; m < 2; ++m) {
        #pragma unroll
        for (int n = 0; n < 9; ++n) acc1[m][n] = fz;
        acc3[m][0] = fz; acc3[m][1] = fz;
    }

    const float* cfb[2];
    #pragma unroll
    for (int m = 0; m < 2; ++m)
        cfb[m] = cf + (rowbase + m * 16 + llo) * 256 + lhi * 8;

    // ---- GEMM1 (cf) + GEMM3 first half: 2-slot / 2-deep prefetch ----
    float4v pa0[2], pa1[2], pb0[2], pb1[2];
    #pragma unroll
    for (int m = 0; m < 2; ++m) {
        pa0[m] = *(const float4v*)(cfb[m]);
        pa1[m] = *(const float4v*)(cfb[m] + 4);
        pb0[m] = *(const float4v*)(cfb[m] + 32);
        pb1[m] = *(const float4v*)(cfb[m] + 36);
    }
    #pragma unroll 1
    for (int kt = 0; kt < 8; kt += 2) {
        short8 a[2];
        a[0] = cvt8(pa0[0], pa1[0]);
        a[1] = cvt8(pa0[1], pa1[1]);
        {
            int o = (kt + 2 < 8 ? kt + 2 : 0) * 32;   // wrap: harmless reload
            #pragma unroll
            for (int m = 0; m < 2; ++m) {
                pa0[m] = *(const float4v*)(cfb[m] + o);
                pa1[m] = *(const float4v*)(cfb[m] + o + 4);
            }
        }
        G1_STEP(kt, a);
        short8 c[2];
        c[0] = cvt8(pb0[0], pb1[0]);
        c[1] = cvt8(pb0[1], pb1[1]);
        {
            int o = (kt + 3 < 8 ? kt + 3 : 1) * 32;
            #pragma unroll
            for (int m = 0; m < 2; ++m) {
                pb0[m] = *(const float4v*)(cfb[m] + o);
                pb1[m] = *(const float4v*)(cfb[m] + o + 4);
            }
        }
        G1_STEP(kt + 1, c);
    }
    // K-tile 8: one-hot action block (k = 256..287, kk = k-256)
    {
        short8 a[2];
        #pragma unroll
        for (int m = 0; m < 2; ++m) {
            #pragma unroll
            for (int i = 0; i < 8; ++i) {
                int kk = lhi * 8 + i;
                a[m][i] = (kk == i0[m] || kk == i1[m] || kk == i2[m])
                              ? (short)0x3F80 : (short)0;
            }
        }
        #pragma unroll
        for (int nt = 0; nt < 9; ++nt) {
            short8 bf = W1FRAG(8, nt);
            acc1[0][nt] = MFMA16(a[0], bf, acc1[0][nt], 0, 0, 0);
            acc1[1][nt] = MFMA16(a[1], bf, acc1[1][nt], 0, 0, 0);
        }
    }

    // ---- epilogue 1: bias + leaky_relu(0.1) -> bf16 -> swizzled LDS ----
    #pragma unroll
    for (int m = 0; m < 2; ++m) {
        #pragma unroll
        for (int nt = 0; nt < 9; ++nt) {
            int col = nt * 16 + llo;
            float bb = b1[col < 140 ? col : 139];
            #pragma unroll
            for (int r = 0; r < 4; ++r) {
                float v = acc1[m][nt][r] + bb;
                v = v > 0.f ? v : 0.1f * v;
                int row = m * 16 + lhi * 4 + r;
                if (nt < 8) {
                    int off = row * 256 + ((col * 2) ^ ((row & 7) << 4));
                    *(uint16_t*)(hA + off) = f2bf(v);
                } else {
                    int off = row * 64 + (((col - 128) * 2) ^ ((row & 3) << 4));
                    *(uint16_t*)(hB + off) = f2bf(v);
                }
            }
        }
    }
    // zero hB cols 144..159 (GEMM2 K-pad; W2p rows there are zero too)
    #pragma unroll
    for (int z = 0; z < 4; ++z) {
        int zz  = lane * 4 + z;            // 0..255
        int row = zz >> 3, d = zz & 7;
        int off = row * 64 + ((32 + d * 4) ^ ((row & 3) << 4));
        *(int*)(hB + off) = 0;
    }
    // NO __syncthreads: h is wave-private; lgkmcnt ordering suffices.

    // ---- GEMM3 second half (nf, k=256..511): 2-slot prefetch ----
    const float* nfb[2];
    #pragma unroll
    for (int m = 0; m < 2; ++m)
        nfb[m] = nf + (rowbase + m * 16 + llo) * 256 + lhi * 8;
    #pragma unroll
    for (int m = 0; m < 2; ++m) {
        pa0[m] = *(const float4v*)(nfb[m]);
        pa1[m] = *(const float4v*)(nfb[m] + 4);
        pb0[m] = *(const float4v*)(nfb[m] + 32);
        pb1[m] = *(const float4v*)(nfb[m] + 36);
    }
    #pragma unroll 1
    for (int kt = 0; kt < 8; kt += 2) {
        short8 a[2];
        a[0] = cvt8(pa0[0], pa1[0]);
        a[1] = cvt8(pa0[1], pa1[1]);
        {
            int o = (kt + 2 < 8 ? kt + 2 : 0) * 32;
            #pragma unroll
            for (int m = 0; m < 2; ++m) {
                pa0[m] = *(const float4v*)(nfb[m] + o);
                pa1[m] = *(const float4v*)(nfb[m] + o + 4);
            }
        }
        G3_STEP(8 + kt, a);
        short8 c[2];
        c[0] = cvt8(pb0[0], pb1[0]);
        c[1] = cvt8(pb0[1], pb1[1]);
        {
            int o = (kt + 3 < 8 ? kt + 3 : 1) * 32;
            #pragma unroll
            for (int m = 0; m < 2; ++m) {
                pb0[m] = *(const float4v*)(nfb[m] + o);
                pb1[m] = *(const float4v*)(nfb[m] + o + 4);
            }
        }
        G3_STEP(8 + kt + 1, c);
    }
    // store action_pred (cols < 24), f32
    float* out2 = out + 67108864L;
    #pragma unroll
    for (int m = 0; m < 2; ++m) {
        #pragma unroll
        for (int nt = 0; nt < 2; ++nt) {
            int col = nt * 16 + llo;
            if (col < 24) {
                float bb = bi[col];
                #pragma unroll
                for (int r = 0; r < 4; ++r) {
                    long row = rowbase + m * 16 + lhi * 4 + r;
                    out2[row * 24 + col] = acc3[m][nt][r] + bb;
                }
            }
        }
    }

    // ---- GEMM2: out0 = leaky(h) @ W2 + b2  (two n-halves to cap VGPRs) ----
    #pragma unroll 1
    for (int pass = 0; pass < 2; ++pass) {
        float4v acc2[2][8];
        #pragma unroll
        for (int m = 0; m < 2; ++m)
            #pragma unroll
            for (int n = 0; n < 8; ++n) acc2[m][n] = fz;

        #pragma unroll
        for (int kt = 0; kt < 5; ++kt) {
            short8 a[2];
            #pragma unroll
            for (int m = 0; m < 2; ++m) {
                int row = m * 16 + llo;
                if (kt < 4) {
                    int off = row * 256 + ((kt * 64 + lhi * 16) ^ ((row & 7) << 4));
                    a[m] = *(const short8*)(hA + off);
                } else {
                    int off = row * 64 + ((lhi * 16) ^ ((row & 3) << 4));
                    a[m] = *(const short8*)(hB + off);
                }
            }
            #pragma unroll
            for (int n = 0; n < 8; ++n) {
                int nt = pass * 8 + n;
                short8 bf = wp[W2_BASE + (kt * 16 + nt) * 64 + lane];
                acc2[0][n] = MFMA16(a[0], bf, acc2[0][n], 0, 0, 0);
                acc2[1][n] = MFMA16(a[1], bf, acc2[1][n], 0, 0, 0);
            }
        }
        #pragma unroll
        for (int m = 0; m < 2; ++m) {
            #pragma unroll
            for (int n = 0; n < 8; ++n) {
                int col = (pass * 8 + n) * 16 + llo;
                float bb = b2[col];
                #pragma unroll
                for (int r = 0; r < 4; ++r) {
                    long row = rowbase + m * 16 + lhi * 4 + r;
                    out[row * 256 + col] = acc2[m][n][r] + bb;
                }
            }
        }
    }
#undef W1FRAG
#undef WIFRAG
#undef G1_STEP
#undef G3_STEP
}

extern "C" void kernel_launch(void* const* d_in, const int* in_sizes, int n_in,
                              void* d_out, int out_size, void* d_ws, size_t ws_size,
                              hipStream_t stream) {
    // Identify inputs by unique element count (verified: matches dict order).
    const float *cf = nullptr, *nf = nullptr, *W1 = nullptr, *b1 = nullptr;
    const float *W2 = nullptr, *b2 = nullptr, *Wi = nullptr, *bi = nullptr;
    const int *ac = nullptr;
    for (int i = 0; i < n_in; ++i) {
        int s = in_sizes[i];
        const void* p = d_in[i];
        switch (s) {
            case 67108864: if (!cf) cf = (const float*)p; else nf = (const float*)p; break;
            case 786432:   ac = (const int*)p;   break;
            case 39200:    W1 = (const float*)p; break;
            case 140:      b1 = (const float*)p; break;
            case 35840:    W2 = (const float*)p; break;
            case 256:      b2 = (const float*)p; break;
            case 12288:    Wi = (const float*)p; break;
            case 24:       bi = (const float*)p; break;
            default: break;
        }
    }
    float* ob = (float*)d_out;

    pack_weights<<<386, 256, 0, stream>>>(W1, W2, Wi);
    icm_main<<<2048, 256, 0, stream>>>(cf, nf, ac, b1, b2, bi, ob);
}

// Round 9
// 205.150 us; speedup vs baseline: 2.1735x; 1.1914x over previous
//
#include <hip/hip_runtime.h>
#include <hip/hip_bf16.h>
#include <stdint.h>

// Round 9: block-shared LDS weight staging (double-buffered), merged GEMM2.
// Theory: r8 waves were ~95% stalled on the per-wave 395KB weight re-stream
// through L1/TA/L2 (all CUs hammering the same 193KB of g_wpack). Staging
// each fragment ONCE per block into LDS cuts per-CU weight requests 4x and
// converts frag reads to conflict-free ds_read_b128.
// LDS: h 40KB (hA/hB per-wave) + 2x16KB staging = 72KB -> 2 blocks/CU.
// Math identical to r6/r7/r8 (PASS, absmax 0.03125).

typedef __attribute__((ext_vector_type(8))) short short8;
typedef __attribute__((ext_vector_type(4))) float float4v;

#define MFMA16 __builtin_amdgcn_mfma_f32_16x16x32_bf16

__device__ __align__(16) uint16_t g_wpack[98816];

__device__ __forceinline__ uint16_t f2bf(float f) {
    __hip_bfloat16 h = __float2bfloat16(f);   // RNE, hw cvt
    return *reinterpret_cast<uint16_t*>(&h);
}

__device__ __forceinline__ short8 cvt8(float4v x0, float4v x1) {
    union { __hip_bfloat162 b2[4]; short8 s; } u;
    u.b2[0] = __float22bfloat162_rn(make_float2(x0[0], x0[1]));
    u.b2[1] = __float22bfloat162_rn(make_float2(x0[2], x0[3]));
    u.b2[2] = __float22bfloat162_rn(make_float2(x1[0], x1[1]));
    u.b2[3] = __float22bfloat162_rn(make_float2(x1[2], x1[3]));
    return u.s;
}

// ---- weight packing into g_wpack (B-fragment order) ----
// W1p: 9kt x 9nt (K=288 pad, N=144 pad) @u16 0      (41472)
// W2p: 5kt x 16nt (K=160 pad, N=256)    @u16 41472  (40960)
// Wip: 16kt x 2nt (K=512,    N=32 pad)  @u16 82432  (16384)
__global__ __launch_bounds__(256) void pack_weights(
    const float* __restrict__ W1, const float* __restrict__ W2,
    const float* __restrict__ Wi)
{
    int e = blockIdx.x * 256 + threadIdx.x;
    const float* W; int NT, Kr, Nr, ld, le, base;
    if (e < 41472)      { W = W1; NT = 9;  Kr = 280; Nr = 140; ld = 140; le = e;         base = 0; }
    else if (e < 82432) { W = W2; NT = 16; Kr = 140; Nr = 256; ld = 256; le = e - 41472; base = 41472; }
    else if (e < 98816) { W = Wi; NT = 2;  Kr = 512; Nr = 24;  ld = 24;  le = e - 82432; base = 82432; }
    else return;
    int i = le & 7, lane = (le >> 3) & 63, frag = le >> 9;
    int kt = frag / NT, nt = frag - kt * NT;
    int k = kt * 32 + ((lane >> 4) << 3) + i;
    int n = nt * 16 + (lane & 15);
    float v = (k < Kr && n < Nr) ? W[k * ld + n] : 0.0f;
    g_wpack[base + le] = f2bf(v);
}

// ---- main fused kernel: 256 threads = 4 waves, each wave 32 rows ----
__global__ __launch_bounds__(256, 2) void icm_main(
    const float* __restrict__ cf, const float* __restrict__ nf,
    const int* __restrict__ act,
    const float* __restrict__ b1, const float* __restrict__ b2,
    const float* __restrict__ bi,
    float* __restrict__ out)
{
    // [0,32768)      hA: per-wave 32 rows x 256B (h cols 0..127, swz (row&7)<<4)
    // [32768,40960)  hB: per-wave 32 rows x  64B (h cols 128..159, swz (row&3)<<4)
    // [40960,57344)  wstA: 16KB weight stage buf 0
    // [57344,73728)  wstB: 16KB weight stage buf 1
    __shared__ char smem[73728];

    const int tid  = threadIdx.x;
    const int wave = tid >> 6;
    const int lane = tid & 63;
    const int lhi  = lane >> 4;   // 0..3
    const int llo  = lane & 15;   // 0..15
    char* hA   = smem + wave * 8192;
    char* hB   = smem + 32768 + wave * 2048;
    char* wstA = smem + 40960;
    char* wstB = smem + 57344;

    const long rowbase = (long)blockIdx.x * 128 + wave * 32;

    // ---- cooperative weight staging helpers (global->reg, reg->LDS) ----
    // Staged region = frags laid out linearly, frag f at byte f*1024.
    // Thread t owns bytes {t*16 + k*4096}.
    short8 wreg[4];

    // phase-1 step: frags 0..8 = W1(kt,0..8) [9216B], 9..10 = Wi(kt,0..1) [2048B]
    auto ld_stage1 = [&](int kt) {
        const char* w1b = (const char*)(g_wpack + kt * 9 * 512);
        const char* wib = (const char*)(g_wpack + 82432 + kt * 2 * 512);
        const int nb = (kt == 8) ? 9216 : 11264;
        #pragma unroll
        for (int k = 0; k < 3; ++k) {
            int b = k * 4096 + tid * 16;
            if (b < nb)
                wreg[k] = (b < 9216) ? *(const short8*)(w1b + b)
                                     : *(const short8*)(wib + (b - 9216));
        }
    };
    auto st_stage1 = [&](char* dst, int kt) {
        const int nb = (kt == 8) ? 9216 : 11264;
        #pragma unroll
        for (int k = 0; k < 3; ++k) {
            int b = k * 4096 + tid * 16;
            if (b < nb) *(short8*)(dst + b) = wreg[k];
        }
    };
    // contiguous 16KB stage (phase 2 Wi[16..31], phase 3 W2 per-kt)
    auto ld_stage_c = [&](const uint16_t* src) {
        #pragma unroll
        for (int k = 0; k < 4; ++k)
            wreg[k] = *(const short8*)((const char*)src + k * 4096 + tid * 16);
    };
    auto st_stage_c = [&](char* dst) {
        #pragma unroll
        for (int k = 0; k < 4; ++k)
            *(short8*)(dst + k * 4096 + tid * 16) = wreg[k];
    };

    // actions for this lane's rows (row = rowbase + m*16 + llo)
    int i0[2], i1[2], i2[2];
    #pragma unroll
    for (int m = 0; m < 2; ++m) {
        long r = rowbase + m * 16 + llo;
        long f = r >> 6; int n = (int)(r & 63);
        i0[m] = act[(f * 3 + 0) * 64 + n];
        i1[m] = act[(f * 3 + 1) * 64 + n] + 8;
        i2[m] = act[(f * 3 + 2) * 64 + n] + 16;
    }

    const float4v fz = {0.f, 0.f, 0.f, 0.f};
    float4v acc1[2][9];
    float4v acc3[2][2];
    #pragma unroll
    for (int m = 0; m < 2; ++m) {
        #pragma unroll
        for (int n = 0; n < 9; ++n) acc1[m][n] = fz;
        acc3[m][0] = fz; acc3[m][1] = fz;
    }

    const float* cfb[2];
    #pragma unroll
    for (int m = 0; m < 2; ++m)
        cfb[m] = cf + (rowbase + m * 16 + llo) * 256 + lhi * 8;

    // ================= Phase 1: GEMM1 + GEMM3a over cf =================
    float4v pa0[2], pa1[2];
    ld_stage1(0);
    #pragma unroll
    for (int m = 0; m < 2; ++m) {
        pa0[m] = *(const float4v*)(cfb[m]);
        pa1[m] = *(const float4v*)(cfb[m] + 4);
    }
    st_stage1(wstA, 0);
    __syncthreads();

    #pragma unroll 1
    for (int kt = 0; kt < 9; ++kt) {
        if (kt < 8) ld_stage1(kt + 1);          // issue next-step weight loads
        const char* wb = (kt & 1) ? wstB : wstA;

        short8 a[2];
        if (kt < 8) {
            a[0] = cvt8(pa0[0], pa1[0]);
            a[1] = cvt8(pa0[1], pa1[1]);
            if (kt < 7) {
                #pragma unroll
                for (int m = 0; m < 2; ++m) {
                    pa0[m] = *(const float4v*)(cfb[m] + (kt + 1) * 32);
                    pa1[m] = *(const float4v*)(cfb[m] + (kt + 1) * 32 + 4);
                }
            }
        } else {
            // one-hot action K-tile (k = 256..287)
            #pragma unroll
            for (int m = 0; m < 2; ++m) {
                #pragma unroll
                for (int i = 0; i < 8; ++i) {
                    int kk = lhi * 8 + i;
                    a[m][i] = (kk == i0[m] || kk == i1[m] || kk == i2[m])
                                  ? (short)0x3F80 : (short)0;
                }
            }
        }

        #pragma unroll
        for (int nt = 0; nt < 9; ++nt) {
            short8 bf = *(const short8*)(wb + (nt << 10) + (lane << 4));
            acc1[0][nt] = MFMA16(a[0], bf, acc1[0][nt], 0, 0, 0);
            acc1[1][nt] = MFMA16(a[1], bf, acc1[1][nt], 0, 0, 0);
        }
        if (kt < 8) {
            #pragma unroll
            for (int nt = 0; nt < 2; ++nt) {
                short8 bf = *(const short8*)(wb + ((9 + nt) << 10) + (lane << 4));
                acc3[0][nt] = MFMA16(a[0], bf, acc3[0][nt], 0, 0, 0);
                acc3[1][nt] = MFMA16(a[1], bf, acc3[1][nt], 0, 0, 0);
            }
            st_stage1(((kt + 1) & 1) ? wstB : wstA, kt + 1);
        }
        __syncthreads();
    }

    // ---- stage phase-2 weights (Wi frags 16..31, 16KB) while doing epilogue ----
    ld_stage_c(g_wpack + 82432 + (16 << 9));

    // epilogue 1: bias + leaky_relu(0.1) -> bf16 -> swizzled per-wave LDS h
    #pragma unroll
    for (int m = 0; m < 2; ++m) {
        #pragma unroll
        for (int nt = 0; nt < 9; ++nt) {
            int col = nt * 16 + llo;
            float bb = b1[col < 140 ? col : 139];
            #pragma unroll
            for (int r = 0; r < 4; ++r) {
                float v = acc1[m][nt][r] + bb;
                v = v > 0.f ? v : 0.1f * v;
                int row = m * 16 + lhi * 4 + r;
                if (nt < 8) {
                    int off = row * 256 + ((col * 2) ^ ((row & 7) << 4));
                    *(uint16_t*)(hA + off) = f2bf(v);
                } else {
                    int off = row * 64 + (((col - 128) * 2) ^ ((row & 3) << 4));
                    *(uint16_t*)(hB + off) = f2bf(v);
                }
            }
        }
    }
    // zero hB cols 144..159 (GEMM2 K-pad; W2p rows there are zero too)
    #pragma unroll
    for (int z = 0; z < 4; ++z) {
        int zz  = lane * 4 + z;            // 0..255
        int row = zz >> 3, d = zz & 7;
        int off = row * 64 + ((32 + d * 4) ^ ((row & 3) << 4));
        *(int*)(hB + off) = 0;
    }

    st_stage_c(wstB);                      // phase-2 weights -> wstB

    // prefetch nf features for kt=0
    const float* nfb[2];
    #pragma unroll
    for (int m = 0; m < 2; ++m)
        nfb[m] = nf + (rowbase + m * 16 + llo) * 256 + lhi * 8;
    #pragma unroll
    for (int m = 0; m < 2; ++m) {
        pa0[m] = *(const float4v*)(nfb[m]);
        pa1[m] = *(const float4v*)(nfb[m] + 4);
    }
    __syncthreads();                       // wstB visible to all waves

    // ================= Phase 2: GEMM3b over nf (no per-step barriers) ========
    ld_stage_c(g_wpack + 41472);           // G2 kt=0 weights (held in regs)
    #pragma unroll 1
    for (int kt = 0; kt < 8; ++kt) {
        short8 a[2];
        a[0] = cvt8(pa0[0], pa1[0]);
        a[1] = cvt8(pa0[1], pa1[1]);
        if (kt < 7) {
            #pragma unroll
            for (int m = 0; m < 2; ++m) {
                pa0[m] = *(const float4v*)(nfb[m] + (kt + 1) * 32);
                pa1[m] = *(const float4v*)(nfb[m] + (kt + 1) * 32 + 4);
            }
        }
        #pragma unroll
        for (int nt = 0; nt < 2; ++nt) {
            short8 bf = *(const short8*)(wstB + (((kt << 1) + nt) << 10) + (lane << 4));
            acc3[0][nt] = MFMA16(a[0], bf, acc3[0][nt], 0, 0, 0);
            acc3[1][nt] = MFMA16(a[1], bf, acc3[1][nt], 0, 0, 0);
        }
    }
    // store action_pred (cols < 24), f32
    float* out2 = out + 67108864L;
    #pragma unroll
    for (int m = 0; m < 2; ++m) {
        #pragma unroll
        for (int nt = 0; nt < 2; ++nt) {
            int col = nt * 16 + llo;
            if (col < 24) {
                float bb = bi[col];
                #pragma unroll
                for (int r = 0; r < 4; ++r) {
                    long row = rowbase + m * 16 + lhi * 4 + r;
                    out2[row * 24 + col] = acc3[m][nt][r] + bb;
                }
            }
        }
    }
    st_stage_c(wstA);                      // G2 kt=0 -> wstA
    __syncthreads();

    // ================= Phase 3: GEMM2 (merged n-passes) =================
    float4v acc2[2][16];
    #pragma unroll
    for (int m = 0; m < 2; ++m)
        #pragma unroll
        for (int n = 0; n < 16; ++n) acc2[m][n] = fz;

    #pragma unroll 1
    for (int kt = 0; kt < 5; ++kt) {
        if (kt < 4) ld_stage_c(g_wpack + 41472 + ((kt + 1) << 13));  // (kt+1)*16*512
        const char* wb = (kt & 1) ? wstB : wstA;

        short8 a[2];
        #pragma unroll
        for (int m = 0; m < 2; ++m) {
            int row = m * 16 + llo;
            if (kt < 4) {
                int off = row * 256 + ((kt * 64 + lhi * 16) ^ ((row & 7) << 4));
                a[m] = *(const short8*)(hA + off);
            } else {
                int off = row * 64 + ((lhi * 16) ^ ((row & 3) << 4));
                a[m] = *(const short8*)(hB + off);
            }
        }
        #pragma unroll
        for (int nt = 0; nt < 16; ++nt) {
            short8 bf = *(const short8*)(wb + (nt << 10) + (lane << 4));
            acc2[0][nt] = MFMA16(a[0], bf, acc2[0][nt], 0, 0, 0);
            acc2[1][nt] = MFMA16(a[1], bf, acc2[1][nt], 0, 0, 0);
        }
        if (kt < 4) st_stage_c(((kt + 1) & 1) ? wstB : wstA);
        __syncthreads();
    }

    // epilogue: out0 stores
    #pragma unroll
    for (int m = 0; m < 2; ++m) {
        #pragma unroll
        for (int n = 0; n < 16; ++n) {
            int col = n * 16 + llo;
            float bb = b2[col];
            #pragma unroll
            for (int r = 0; r < 4; ++r) {
                long row = rowbase + m * 16 + lhi * 4 + r;
                out[row * 256 + col] = acc2[m][n][r] + bb;
            }
        }
    }
}

extern "C" void kernel_launch(void* const* d_in, const int* in_sizes, int n_in,
                              void* d_out, int out_size, void* d_ws, size_t ws_size,
                              hipStream_t stream) {
    // Identify inputs by unique element count (verified: matches dict order).
    const float *cf = nullptr, *nf = nullptr, *W1 = nullptr, *b1 = nullptr;
    const float *W2 = nullptr, *b2 = nullptr, *Wi = nullptr, *bi = nullptr;
    const int *ac = nullptr;
    for (int i = 0; i < n_in; ++i) {
        int s = in_sizes[i];
        const void* p = d_in[i];
        switch (s) {
            case 67108864: if (!cf) cf = (const float*)p; else nf = (const float*)p; break;
            case 786432:   ac = (const int*)p;   break;
            case 39200:    W1 = (const float*)p; break;
            case 140:      b1 = (const float*)p; break;
            case 35840:    W2 = (const float*)p; break;
            case 256:      b2 = (const float*)p; break;
            case 12288:    Wi = (const float*)p; break;
            case 24:       bi = (const float*)p; break;
            default: break;
        }
    }
    float* ob = (float*)d_out;

    pack_weights<<<386, 256, 0, stream>>>(W1, W2, Wi);
    icm_main<<<2048, 256, 0, stream>>>(cf, nf, ac, b1, b2, bi, ob);
}

// Round 12
// 201.011 us; speedup vs baseline: 2.2183x; 1.0206x over previous
//
#include <hip/hip_runtime.h>
#include <hip/hip_bf16.h>
#include <stdint.h>

// Round 12: r9's PASSING __syncthreads structure + global_load_lds weight
// staging (no reg round-trip -> no mid-step vmcnt drain; loads stay in flight
// until the end-of-step barrier -> high in-flight duty cycle).
// r10/r11's raw-SBAR counted-vmcnt schedule abandoned (unresolvable race,
// m152 lesson); their gl_lds ADDRESSING is reused verbatim here under full
// __syncthreads fencing. Math identical to r6-r9 (PASS, absmax 0.03125).

typedef __attribute__((ext_vector_type(8))) short short8;
typedef __attribute__((ext_vector_type(4))) float float4v;

#define MFMA16 __builtin_amdgcn_mfma_f32_16x16x32_bf16

__device__ __align__(16) uint16_t g_wpack[98816];

__device__ __forceinline__ void gl_lds16(const void* g, void* l) {
    __builtin_amdgcn_global_load_lds(
        (const __attribute__((address_space(1))) unsigned int*)g,
        (__attribute__((address_space(3))) unsigned int*)l, 16, 0, 0);
}

__device__ __forceinline__ uint16_t f2bf(float f) {
    __hip_bfloat16 h = __float2bfloat16(f);   // RNE, hw cvt
    return *reinterpret_cast<uint16_t*>(&h);
}

__device__ __forceinline__ short8 cvt8(float4v x0, float4v x1) {
    union { __hip_bfloat162 b2[4]; short8 s; } u;
    u.b2[0] = __float22bfloat162_rn(make_float2(x0[0], x0[1]));
    u.b2[1] = __float22bfloat162_rn(make_float2(x0[2], x0[3]));
    u.b2[2] = __float22bfloat162_rn(make_float2(x1[0], x1[1]));
    u.b2[3] = __float22bfloat162_rn(make_float2(x1[2], x1[3]));
    return u.s;
}

// ---- weight packing into g_wpack (B-fragment order) ----
// W1p: 9kt x 9nt (K=288 pad, N=144 pad) @u16 0      (41472)
// W2p: 5kt x 16nt (K=160 pad, N=256)    @u16 41472  (40960)
// Wip: 16kt x 2nt (K=512,    N=32 pad)  @u16 82432  (16384)
__global__ __launch_bounds__(256) void pack_weights(
    const float* __restrict__ W1, const float* __restrict__ W2,
    const float* __restrict__ Wi)
{
    int e = blockIdx.x * 256 + threadIdx.x;
    const float* W; int NT, Kr, Nr, ld, le, base;
    if (e < 41472)      { W = W1; NT = 9;  Kr = 280; Nr = 140; ld = 140; le = e;         base = 0; }
    else if (e < 82432) { W = W2; NT = 16; Kr = 140; Nr = 256; ld = 256; le = e - 41472; base = 41472; }
    else if (e < 98816) { W = Wi; NT = 2;  Kr = 512; Nr = 24;  ld = 24;  le = e - 82432; base = 82432; }
    else return;
    int i = le & 7, lane = (le >> 3) & 63, frag = le >> 9;
    int kt = frag / NT, nt = frag - kt * NT;
    int k = kt * 32 + ((lane >> 4) << 3) + i;
    int n = nt * 16 + (lane & 15);
    float v = (k < Kr && n < Nr) ? W[k * ld + n] : 0.0f;
    g_wpack[base + le] = f2bf(v);
}

// ---- main fused kernel: 256 threads = 4 waves, each wave 32 rows ----
__global__ __launch_bounds__(256, 2) void icm_main(
    const float* __restrict__ cf, const float* __restrict__ nf,
    const int* __restrict__ act,
    const float* __restrict__ b1, const float* __restrict__ b2,
    const float* __restrict__ bi,
    float* __restrict__ out)
{
    // [0,32768)      hA: per-wave 32 rows x 256B (h cols 0..127, swz (row&7)<<4)
    // [32768,40960)  hB: per-wave 32 rows x  64B (h cols 128..159, swz (row&3)<<4)
    // [40960,57344)  wstA / [57344,73728) wstB: 16KB weight stage buffers
    __shared__ char smem[73728];

    const int tid  = threadIdx.x;
    const int wave = tid >> 6;
    const int lane = tid & 63;
    const int lhi  = lane >> 4;   // 0..3
    const int llo  = lane & 15;   // 0..15
    char* hA   = smem + wave * 8192;
    char* hB   = smem + 32768 + wave * 2048;
    char* wstA = smem + 40960;
    char* wstB = smem + 57344;

    const long rowbase = (long)blockIdx.x * 128 + wave * 32;
    const char* gw = (const char*)g_wpack;

    // phase-1 staging: frag f at stage byte f*1024; W1(kt,0..8)=9216B, Wi(kt,0..1)
    auto stage1 = [&](char* dst, int kt) {
        const char* w1b = gw + kt * 9216;
        const char* wib = gw + 164864 + kt * 2048;
        const int nb = (kt == 8) ? 9216 : 11264;
        #pragma unroll
        for (int k = 0; k < 3; ++k) {
            int b = k * 4096 + wave * 1024;          // wave-uniform LDS slice
            if (b < nb) {
                const char* src = (b < 9216) ? (w1b + b) : (wib + (b - 9216));
                gl_lds16(src + lane * 16, dst + b);
            }
        }
    };
    // contiguous 16KB stage (phase-2 Wi[16..31], phase-3 W2 per-kt)
    auto stage16 = [&](char* dst, const char* src) {
        #pragma unroll
        for (int k = 0; k < 4; ++k) {
            int b = k * 4096 + wave * 1024;
            gl_lds16(src + b + lane * 16, dst + b);
        }
    };

    // prologue scalars: actions, b1, bi
    int i0[2], i1[2], i2[2];
    #pragma unroll
    for (int m = 0; m < 2; ++m) {
        long r = rowbase + m * 16 + llo;
        long f = r >> 6; int n = (int)(r & 63);
        i0[m] = act[(f * 3 + 0) * 64 + n];
        i1[m] = act[(f * 3 + 1) * 64 + n] + 8;
        i2[m] = act[(f * 3 + 2) * 64 + n] + 16;
    }
    float bb1[9];
    #pragma unroll
    for (int nt = 0; nt < 9; ++nt) {
        int col = nt * 16 + llo;
        bb1[nt] = b1[col < 140 ? col : 139];
    }
    float bi0 = bi[llo];
    float bi1 = (llo < 8) ? bi[16 + llo] : 0.f;

    const float4v fz = {0.f, 0.f, 0.f, 0.f};
    float4v acc1[2][9];
    float4v acc3[2][2];
    #pragma unroll
    for (int m = 0; m < 2; ++m) {
        #pragma unroll
        for (int n = 0; n < 9; ++n) acc1[m][n] = fz;
        acc3[m][0] = fz; acc3[m][1] = fz;
    }

    const float* cfb[2];
    #pragma unroll
    for (int m = 0; m < 2; ++m)
        cfb[m] = cf + (rowbase + m * 16 + llo) * 256 + lhi * 8;

    // ================= Phase 1: GEMM1 + GEMM3a over cf =================
    float4v pa0[2], pa1[2], pb0[2], pb1[2];
    stage1(wstA, 0);
    #pragma unroll
    for (int m = 0; m < 2; ++m) {
        pa0[m] = *(const float4v*)(cfb[m]);
        pa1[m] = *(const float4v*)(cfb[m] + 4);
        pb0[m] = *(const float4v*)(cfb[m] + 32);
        pb1[m] = *(const float4v*)(cfb[m] + 36);
    }
    __syncthreads();

    #pragma unroll 1
    for (int kt = 0; kt < 8; ++kt) {
        stage1((kt & 1) ? wstA : wstB, kt + 1);     // gl_lds: issue first
        const char* wb = (kt & 1) ? wstB : wstA;
        short8 a[2];
        if (kt & 1) { a[0] = cvt8(pb0[0], pb1[0]); a[1] = cvt8(pb0[1], pb1[1]); }
        else        { a[0] = cvt8(pa0[0], pa1[0]); a[1] = cvt8(pa0[1], pa1[1]); }
        if (kt <= 5) {                              // refill same slot for kt+2
            int o = (kt + 2) * 32;
            if (kt & 1) {
                #pragma unroll
                for (int m = 0; m < 2; ++m) {
                    pb0[m] = *(const float4v*)(cfb[m] + o);
                    pb1[m] = *(const float4v*)(cfb[m] + o + 4);
                }
            } else {
                #pragma unroll
                for (int m = 0; m < 2; ++m) {
                    pa0[m] = *(const float4v*)(cfb[m] + o);
                    pa1[m] = *(const float4v*)(cfb[m] + o + 4);
                }
            }
        }
        #pragma unroll
        for (int nt = 0; nt < 9; ++nt) {
            short8 bf = *(const short8*)(wb + (nt << 10) + (lane << 4));
            acc1[0][nt] = MFMA16(a[0], bf, acc1[0][nt], 0, 0, 0);
            acc1[1][nt] = MFMA16(a[1], bf, acc1[1][nt], 0, 0, 0);
        }
        #pragma unroll
        for (int nt = 0; nt < 2; ++nt) {
            short8 bf = *(const short8*)(wb + ((9 + nt) << 10) + (lane << 4));
            acc3[0][nt] = MFMA16(a[0], bf, acc3[0][nt], 0, 0, 0);
            acc3[1][nt] = MFMA16(a[1], bf, acc3[1][nt], 0, 0, 0);
        }
        __syncthreads();                            // drains gl_lds + fences
    }
    // kt = 8: one-hot action K-tile (reads wstA, staged at kt=7)
    {
        short8 a[2];
        #pragma unroll
        for (int m = 0; m < 2; ++m) {
            #pragma unroll
            for (int i = 0; i < 8; ++i) {
                int kk = lhi * 8 + i;
                a[m][i] = (kk == i0[m] || kk == i1[m] || kk == i2[m])
                              ? (short)0x3F80 : (short)0;
            }
        }
        #pragma unroll
        for (int nt = 0; nt < 9; ++nt) {
            short8 bf = *(const short8*)(wstA + (nt << 10) + (lane << 4));
            acc1[0][nt] = MFMA16(a[0], bf, acc1[0][nt], 0, 0, 0);
            acc1[1][nt] = MFMA16(a[1], bf, acc1[1][nt], 0, 0, 0);
        }
    }
    __syncthreads();   // all reads of wstA/wstB done -> safe to restage

    // ---- stage phase-2 weights + W2 kt0 (gl_lds, fly under epilogue) ----
    stage16(wstB, gw + 164864 + 16384);    // Wi frags 16..31
    stage16(wstA, gw + 82944);             // W2 kt0

    // epilogue 1: bias + leaky_relu(0.1) -> bf16 -> swizzled per-wave LDS h
    #pragma unroll
    for (int m = 0; m < 2; ++m) {
        #pragma unroll
        for (int nt = 0; nt < 9; ++nt) {
            int col = nt * 16 + llo;
            #pragma unroll
            for (int r = 0; r < 4; ++r) {
                float v = acc1[m][nt][r] + bb1[nt];
                v = v > 0.f ? v : 0.1f * v;
                int row = m * 16 + lhi * 4 + r;
                if (nt < 8) {
                    int off = row * 256 + ((col * 2) ^ ((row & 7) << 4));
                    *(uint16_t*)(hA + off) = f2bf(v);
                } else {
                    int off = row * 64 + (((col - 128) * 2) ^ ((row & 3) << 4));
                    *(uint16_t*)(hB + off) = f2bf(v);
                }
            }
        }
    }
    // zero hB cols 144..159 (GEMM2 K-pad)
    #pragma unroll
    for (int z = 0; z < 4; ++z) {
        int zz  = lane * 4 + z;
        int row = zz >> 3, d = zz & 7;
        int off = row * 64 + ((32 + d * 4) ^ ((row & 3) << 4));
        *(int*)(hB + off) = 0;
    }

    // nf features for kt0/kt1
    const float* nfb[2];
    #pragma unroll
    for (int m = 0; m < 2; ++m)
        nfb[m] = nf + (rowbase + m * 16 + llo) * 256 + lhi * 8;
    #pragma unroll
    for (int m = 0; m < 2; ++m) {
        pa0[m] = *(const float4v*)(nfb[m]);
        pa1[m] = *(const float4v*)(nfb[m] + 4);
        pb0[m] = *(const float4v*)(nfb[m] + 32);
        pb1[m] = *(const float4v*)(nfb[m] + 36);
    }
    __syncthreads();                       // staging visible to all waves

    // ================= Phase 2: GEMM3b over nf (no barriers) =================
    #pragma unroll 1
    for (int kt = 0; kt < 8; ++kt) {
        short8 a[2];
        if (kt & 1) { a[0] = cvt8(pb0[0], pb1[0]); a[1] = cvt8(pb0[1], pb1[1]); }
        else        { a[0] = cvt8(pa0[0], pa1[0]); a[1] = cvt8(pa0[1], pa1[1]); }
        if (kt <= 5) {
            int o = (kt + 2) * 32;
            if (kt & 1) {
                #pragma unroll
                for (int m = 0; m < 2; ++m) {
                    pb0[m] = *(const float4v*)(nfb[m] + o);
                    pb1[m] = *(const float4v*)(nfb[m] + o + 4);
                }
            } else {
                #pragma unroll
                for (int m = 0; m < 2; ++m) {
                    pa0[m] = *(const float4v*)(nfb[m] + o);
                    pa1[m] = *(const float4v*)(nfb[m] + o + 4);
                }
            }
        }
        #pragma unroll
        for (int nt = 0; nt < 2; ++nt) {
            short8 bf = *(const short8*)(wstB + (((kt << 1) + nt) << 10) + (lane << 4));
            acc3[0][nt] = MFMA16(a[0], bf, acc3[0][nt], 0, 0, 0);
            acc3[1][nt] = MFMA16(a[1], bf, acc3[1][nt], 0, 0, 0);
        }
    }
    // store action_pred (cols < 24), f32
    float* out2 = out + 67108864L;
    #pragma unroll
    for (int m = 0; m < 2; ++m) {
        #pragma unroll
        for (int nt = 0; nt < 2; ++nt) {
            int col = nt * 16 + llo;
            if (col < 24) {
                float bb = (nt == 0) ? bi0 : bi1;
                #pragma unroll
                for (int r = 0; r < 4; ++r) {
                    long row = rowbase + m * 16 + lhi * 4 + r;
                    out2[row * 24 + col] = acc3[m][nt][r] + bb;
                }
            }
        }
    }
    __syncthreads();   // all reads of wstB done -> phase 3 may restage

    // ================= Phase 3: GEMM2 (merged n-passes) =================
    float4v acc2[2][16];
    #pragma unroll
    for (int m = 0; m < 2; ++m)
        #pragma unroll
        for (int n = 0; n < 16; ++n) acc2[m][n] = fz;

    #pragma unroll 1
    for (int kt = 0; kt < 5; ++kt) {
        if (kt < 4) stage16((kt & 1) ? wstA : wstB, gw + 82944 + (kt + 1) * 16384);
        const char* wb = (kt & 1) ? wstB : wstA;
        short8 a[2];
        #pragma unroll
        for (int m = 0; m < 2; ++m) {
            int row = m * 16 + llo;
            if (kt < 4) {
                int off = row * 256 + ((kt * 64 + lhi * 16) ^ ((row & 7) << 4));
                a[m] = *(const short8*)(hA + off);
            } else {
                int off = row * 64 + ((lhi * 16) ^ ((row & 3) << 4));
                a[m] = *(const short8*)(hB + off);
            }
        }
        #pragma unroll
        for (int nt = 0; nt < 16; ++nt) {
            short8 bf = *(const short8*)(wb + (nt << 10) + (lane << 4));
            acc2[0][nt] = MFMA16(a[0], bf, acc2[0][nt], 0, 0, 0);
            acc2[1][nt] = MFMA16(a[1], bf, acc2[1][nt], 0, 0, 0);
        }
        if (kt < 4) __syncthreads();
    }

    // epilogue: out0 stores
    #pragma unroll
    for (int m = 0; m < 2; ++m) {
        #pragma unroll
        for (int n = 0; n < 16; ++n) {
            int col = n * 16 + llo;
            float bb = b2[col];
            #pragma unroll
            for (int r = 0; r < 4; ++r) {
                long row = rowbase + m * 16 + lhi * 4 + r;
                out[row * 256 + col] = acc2[m][n][r] + bb;
            }
        }
    }
}

extern "C" void kernel_launch(void* const* d_in, const int* in_sizes, int n_in,
                              void* d_out, int out_size, void* d_ws, size_t ws_size,
                              hipStream_t stream) {
    // Identify inputs by unique element count (verified: matches dict order).
    const float *cf = nullptr, *nf = nullptr, *W1 = nullptr, *b1 = nullptr;
    const float *W2 = nullptr, *b2 = nullptr, *Wi = nullptr, *bi = nullptr;
    const int *ac = nullptr;
    for (int i = 0; i < n_in; ++i) {
        int s = in_sizes[i];
        const void* p = d_in[i];
        switch (s) {
            case 67108864: if (!cf) cf = (const float*)p; else nf = (const float*)p; break;
            case 786432:   ac = (const int*)p;   break;
            case 39200:    W1 = (const float*)p; break;
            case 140:      b1 = (const float*)p; break;
            case 35840:    W2 = (const float*)p; break;
            case 256:      b2 = (const float*)p; break;
            case 12288:    Wi = (const float*)p; break;
            case 24:       bi = (const float*)p; break;
            default: break;
        }
    }
    float* ob = (float*)d_out;

    pack_weights<<<386, 256, 0, stream>>>(W1, W2, Wi);
    icm_main<<<2048, 256, 0, stream>>>(cf, nf, ac, b1, b2, bi, ob);
}